// Round 9
// baseline (181.487 us; speedup 1.0000x reference)
//
#include <hip/hip_runtime.h>
#include <stdint.h>

#define T_STEPS 256
#define BATCH   2048
#define ISZ     11
#define HID     64
#define PHOR    12
#define BPB     4     // batches per block -> 512 blocks = 2 per CU

typedef __attribute__((ext_vector_type(8))) short short8;
typedef __attribute__((ext_vector_type(4))) float f32x4;

union S8U { short8 s; uint32_t u[4]; };

__device__ __forceinline__ uint32_t cvt_pk_bf16(float lo, float hi) {
  uint32_t r;
  asm("v_cvt_pk_bf16_f32 %0, %1, %2" : "=v"(r) : "v"(lo), "v"(hi));
  return r;
}
// sigmoid with pre-scaled input: z = -log2(e)*v  ->  sigm = 1/(1+2^z)
__device__ __forceinline__ float sigm_z(float z) {
  return __builtin_amdgcn_rcpf(1.0f + __builtin_amdgcn_exp2f(z));
}
__device__ __forceinline__ void plswap16(float &a, float &b) {
  asm("v_permlane16_swap_b32 %0, %1" : "+v"(a), "+v"(b));
}
__device__ __forceinline__ void plswap32(float &a, float &b) {
  asm("v_permlane32_swap_b32 %0, %1" : "+v"(a), "+v"(b));
}
// Barrier draining LDS only — global loads stay in flight (no vmcnt(0)).
__device__ __forceinline__ void lds_barrier() {
  asm volatile("s_waitcnt lgkmcnt(0)" ::: "memory");
  __builtin_amdgcn_s_barrier();
  asm volatile("" ::: "memory");
}

// 4 batches/block, 512 blocks (2/CU), 4 waves, 1 barrier/step. Wave wv owns
// hidden units 16wv..16wv+15 (gate tiles {wv,4+wv,8+wv,12+wv}). Gates for
// the 4 real batch rows (D rows 0-3, regs of lg=0 lanes) are spread to one
// cell per lane (lane(lc,lg) -> batch lg, unit 16wv+lc) via the R7-verified
// 3-permswap REDIST. Cell cost: 5 transcendentals/lane/step.
__global__ __launch_bounds__(256)
void lstm_fused(const float* __restrict__ x, const float* __restrict__ y,
                const float* __restrict__ Wih_e, const float* __restrict__ Whh_e,
                const float* __restrict__ b_e,
                const float* __restrict__ Wih_d, const float* __restrict__ Whh_d,
                const float* __restrict__ b_d,
                const float* __restrict__ Wfc, const float* __restrict__ bfc,
                float* __restrict__ out)
{
  const int tid  = threadIdx.x;
  const int lane = tid & 63;
  const int wv   = tid >> 6;      // 0..3
  const int lc   = lane & 15;     // A-row (batch) / D-col (unit) within tile
  const int lg   = lane >> 4;     // k-group; after REDIST: batch index 0..3
  const int b0   = blockIdx.x * BPB;
  const int j    = 16*wv + lc;    // hidden unit this lane owns

  // h: [buf][16 rows (4 real)][64 units] bf16, XOR-swizzled 16B granules:
  // elem (b,u) at b*64 + ((u>>3)^(b&7))*8 + (u&7). Rows 4-15 stay zero.
  __shared__ __align__(16) unsigned short hsm[2][16][64];
  __shared__ float red[2][4][BPB];
  unsigned short* hb = &hsm[0][0][0];
  for (int idx = tid; idx < 2*16*64; idx += 256) hb[idx] = 0;

  const int rof0 = lc*64 + ((lg     ^ (lc&7)))*8;  // A-frag units lg*8..+7
  const int rof1 = lc*64 + (((4+lg) ^ (lc&7)))*8;  // units 32+lg*8..+7
  const int wof  = lg*64 + (((j>>3) ^ (lg&7))*8) + (j&7);   // batch=lg, rows 0-3

  // gate scales: PyTorch order i,f,g,o — sigm: -log2e, tanh: -2log2e
  const float SC[4] = {-1.44269504f, -1.44269504f, -2.88539008f, -1.44269504f};

  // ---- encoder weight fragments (prescaled, persistent in VGPRs) ----
  short8 Bh[4][2], Bx[4];
  float bias[4];
  #pragma unroll
  for (int i = 0; i < 4; ++i) {
    const int r = 64*i + j;
    const float s = SC[i];
    #pragma unroll
    for (int f = 0; f < 2; ++f) {
      S8U v;
      #pragma unroll
      for (int e2 = 0; e2 < 4; ++e2)
        v.u[e2] = cvt_pk_bf16(Whh_e[r*HID + f*32 + lg*8 + 2*e2]*s,
                              Whh_e[r*HID + f*32 + lg*8 + 2*e2 + 1]*s);
      Bh[i][f] = v.s;
    }
    S8U vx;
    #pragma unroll
    for (int e2 = 0; e2 < 4; ++e2) {
      const int k0 = lg*8 + 2*e2, k1 = k0 + 1;
      vx.u[e2] = cvt_pk_bf16(k0 < ISZ ? Wih_e[r*ISZ + k0]*s : 0.f,
                             k1 < ISZ ? Wih_e[r*ISZ + k1]*s : 0.f);
    }
    Bx[i] = vx.s;
    bias[i] = b_e[r]*s;
  }

  // ---- x pipeline: ax[t&1]=x(t) packed; xf[t&1]=x(t+2) f32 ----
  const float* xrow = x + (size_t)(b0 + (lc & 3))*ISZ;
  float xf[2][8];
  S8U ax[2];
  #pragma unroll
  for (int s = 0; s < 2; ++s) {
    float tmp[8];
    #pragma unroll
    for (int e = 0; e < 8; ++e) {
      const int k = lg*8 + e;
      tmp[e] = (k < ISZ) ? xrow[(size_t)s*BATCH*ISZ + k] : 0.f;
      xf[s][e] = 0.f;
    }
    #pragma unroll
    for (int e2 = 0; e2 < 4; ++e2) ax[s].u[e2] = cvt_pk_bf16(tmp[2*e2], tmp[2*e2+1]);
  }
  #pragma unroll
  for (int s = 0; s < 2; ++s)
    #pragma unroll
    for (int e = 0; e < 8; ++e) {
      const int k = lg*8 + e;
      if (k < ISZ) xf[s][e] = xrow[(size_t)(2+s)*BATCH*ISZ + k];
    }
  const float* xnl = xrow + (size_t)4*BATCH*ISZ;

  float cc = 0.f;    // one cell per lane: batch lg, unit j

#define REDIST(GACC, W) do { \
    _Pragma("unroll") \
    for (int i_ = 0; i_ < 4; ++i_) { \
      float r0 = GACC[i_][0], r1 = GACC[i_][1], r2 = GACC[i_][2], r3 = GACC[i_][3]; \
      plswap16(r0, r1); \
      plswap16(r2, r3); \
      plswap32(r0, r2); \
      W[i_] = r0; \
    } \
  } while (0)

  // ---- encoder recurrence: 1 barrier/step, double-buffered h ----
  #pragma unroll 2
  for (int t = 0; t < T_STEPS; ++t) {
    const int s = t & 1;
    lds_barrier();                 // h(t) (and first-iter zero-init) visible
    const unsigned short* hr = hb + s*1024;
    unsigned short*       hw = hb + (s^1)*1024;
    short8 ah0 = *(const short8*)(hr + rof0);
    short8 ah1 = *(const short8*)(hr + rof1);

    // x-MFMA for THIS step + pipeline maintenance (independent of ds_reads)
    f32x4 gacc[4];
    #pragma unroll
    for (int i = 0; i < 4; ++i) {
      f32x4 a = {bias[i], bias[i], bias[i], bias[i]};
      gacc[i] = __builtin_amdgcn_mfma_f32_16x16x32_bf16(ax[s].s, Bx[i], a, 0, 0, 0);
    }
    #pragma unroll
    for (int e2 = 0; e2 < 4; ++e2) ax[s].u[e2] = cvt_pk_bf16(xf[s][2*e2], xf[s][2*e2+1]);
    if (t + 4 < T_STEPS) {
      #pragma unroll
      for (int e = 0; e < 8; ++e) { const int k = lg*8 + e; if (k < ISZ) xf[s][e] = xnl[k]; }
    }
    xnl += BATCH*ISZ;

    // h-MFMAs chained through C (compiler inserts the lgkm wait here)
    #pragma unroll
    for (int i = 0; i < 4; ++i) {
      gacc[i] = __builtin_amdgcn_mfma_f32_16x16x32_bf16(ah0, Bh[i][0], gacc[i], 0, 0, 0);
      gacc[i] = __builtin_amdgcn_mfma_f32_16x16x32_bf16(ah1, Bh[i][1], gacc[i], 0, 0, 0);
    }

    // redistribute rows 0-3 -> 1 cell/lane (batch=lg, unit=j)
    float w[4];
    REDIST(gacc, w);
    const float iv = sigm_z(w[0]);
    const float fv = sigm_z(w[1]);
    const float gv = 2.f*sigm_z(w[2]) - 1.f;
    const float ov = sigm_z(w[3]);
    cc = fv*cc + iv*gv;
    const float th = 2.f*sigm_z(cc * -2.88539008f) - 1.f;
    const float hv = ov*th;

    hw[wof] = (unsigned short)cvt_pk_bf16(hv, hv);
  }

  // ---- decoder weights (prescaled) ----
  #pragma unroll
  for (int i = 0; i < 4; ++i) {
    const int r = 64*i + j;
    const float s = SC[i];
    #pragma unroll
    for (int f = 0; f < 2; ++f) {
      S8U v;
      #pragma unroll
      for (int e2 = 0; e2 < 4; ++e2)
        v.u[e2] = cvt_pk_bf16(Whh_d[r*HID + f*32 + lg*8 + 2*e2]*s,
                              Whh_d[r*HID + f*32 + lg*8 + 2*e2 + 1]*s);
      Bh[i][f] = v.s;
    }
  }
  f32x4 gi[4];   // C-init: real batches are rows 0-3 (lg==0 regs); rest bias-only
  #pragma unroll
  for (int i = 0; i < 4; ++i) {
    const int r = 64*i + j;
    const float wd = Wih_d[r]*SC[i], bd = b_d[r]*SC[i];
    #pragma unroll
    for (int g = 0; g < 4; ++g) {
      const float yv = (lg == 0) ? y[b0 + g] : 0.f;
      gi[i][g] = yv*wd + bd;
    }
  }
  const float wfc = Wfc[j];
  const float bfv = bfc[0];

  // ---- decoder: h(T) in buf0 (T even); 2 barriers/step (12 steps) ----
  for (int p = 0; p < PHOR; ++p) {
    const int pb = p & 1;
    lds_barrier();               // h(p) visible
    const unsigned short* hr = hb + pb*1024;
    unsigned short*       hw = hb + (pb^1)*1024;
    short8 ah0 = *(const short8*)(hr + rof0);
    short8 ah1 = *(const short8*)(hr + rof1);
    f32x4 gacc[4];
    #pragma unroll
    for (int i = 0; i < 4; ++i) {
      gacc[i] = __builtin_amdgcn_mfma_f32_16x16x32_bf16(ah0, Bh[i][0], gi[i], 0, 0, 0);
      gacc[i] = __builtin_amdgcn_mfma_f32_16x16x32_bf16(ah1, Bh[i][1], gacc[i], 0, 0, 0);
    }
    float w[4];
    REDIST(gacc, w);
    const float iv = sigm_z(w[0]);
    const float fv = sigm_z(w[1]);
    const float gv = 2.f*sigm_z(w[2]) - 1.f;
    const float ov = sigm_z(w[3]);
    cc = fv*cc + iv*gv;
    const float th = 2.f*sigm_z(cc * -2.88539008f) - 1.f;
    const float hv = ov*th;

    hw[wof] = (unsigned short)cvt_pk_bf16(hv, hv);

    float part = hv * wfc;
    #pragma unroll
    for (int m = 1; m <= 8; m <<= 1)
      part += __shfl_xor(part, m, 64);
    if (lc == 0) red[pb][wv][lg] = part;
    lds_barrier();               // red + h(p+1) visible
    if (tid < BPB)
      out[(size_t)p*BATCH + b0 + tid] = bfv + red[pb][0][tid] + red[pb][1][tid]
                                            + red[pb][2][tid] + red[pb][3][tid];
  }
#undef REDIST
}

extern "C" void kernel_launch(void* const* d_in, const int* in_sizes, int n_in,
                              void* d_out, int out_size, void* d_ws, size_t ws_size,
                              hipStream_t stream) {
  const float* x     = (const float*)d_in[0];
  const float* y     = (const float*)d_in[1];
  // d_in[2] = teacher_force (0 in setup; inference branch only)
  const float* Wih_e = (const float*)d_in[3];
  const float* Whh_e = (const float*)d_in[4];
  const float* b_e   = (const float*)d_in[5];
  const float* Wih_d = (const float*)d_in[6];
  const float* Whh_d = (const float*)d_in[7];
  const float* b_d   = (const float*)d_in[8];
  const float* Wfc   = (const float*)d_in[9];
  const float* bfc   = (const float*)d_in[10];
  float* out = (float*)d_out;

  lstm_fused<<<dim3(BATCH/BPB), dim3(256), 0, stream>>>(
      x, y, Wih_e, Whh_e, b_e, Wih_d, Whh_d, b_d, Wfc, bfc, out);
}

// Round 11
// 123.144 us; speedup vs baseline: 1.4738x; 1.4738x over previous
//
#include <hip/hip_runtime.h>
#include <stdint.h>

#define T_STEPS 256
#define BATCH   2048
#define ISZ     11
#define HID     64
#define PHOR    12
#define BPB     8     // batches per block -> 256 blocks = 1 per CU

typedef __attribute__((ext_vector_type(8))) short short8;
typedef __attribute__((ext_vector_type(4))) float f32x4;

union S8U { short8 s; uint32_t u[4]; };

__device__ __forceinline__ uint32_t cvt_pk_bf16(float lo, float hi) {
  uint32_t r;
  asm("v_cvt_pk_bf16_f32 %0, %1, %2" : "=v"(r) : "v"(lo), "v"(hi));
  return r;
}
// sigmoid with pre-scaled input: z = -log2(e)*v  ->  sigm = 1/(1+2^z)
__device__ __forceinline__ float sigm_z(float z) {
  return __builtin_amdgcn_rcpf(1.0f + __builtin_amdgcn_exp2f(z));
}
// D0.hi <-> D1.lo half-wave swap: after call, a[l<32]=a, a[l>=32]=b[l-32].
__device__ __forceinline__ float permswap(float a, float b) {
  asm("v_permlane32_swap_b32 %0, %1" : "+v"(a), "+v"(b));
  return a;
}
// Barrier draining LDS only — global loads stay in flight (no vmcnt(0)).
__device__ __forceinline__ void lds_barrier() {
  asm volatile("s_waitcnt lgkmcnt(0)" ::: "memory");
  __builtin_amdgcn_s_barrier();
  asm volatile("" ::: "memory");
}

// R6 (168 us) verbatim, except x comes from a one-time LDS pre-stage
// (bf16, A-fragment order [t][b][k16]) instead of a per-step global-load
// pipeline. The conditional xs load is guarded (no OOB pointer is ever
// formed - lg>=2 lanes supply structural zeros for k>=16).
__global__ __launch_bounds__(256)
void lstm_fused(const float* __restrict__ x, const float* __restrict__ y,
                const float* __restrict__ Wih_e, const float* __restrict__ Whh_e,
                const float* __restrict__ b_e,
                const float* __restrict__ Wih_d, const float* __restrict__ Whh_d,
                const float* __restrict__ b_d,
                const float* __restrict__ Wfc, const float* __restrict__ bfc,
                float* __restrict__ out)
{
  const int tid  = threadIdx.x;
  const int lane = tid & 63;
  const int wv   = tid >> 6;      // 0..3
  const int lc   = lane & 15;     // A-row (batch) / D-col (unit) within tile
  const int lg   = lane >> 4;     // k-group / m-group
  const int b0   = blockIdx.x * BPB;
  const int j    = 16*wv + lc;    // hidden unit this lane owns
  const int bmA  = ((lg & 1) << 2) | (lg & 2);    // 0,4,2,6 per lg
  const int bmB  = bmA + 1;

  // h: [buf][16 rows (8 real)][64 units] bf16, XOR-swizzled 16B granules:
  // elem (b,u) at b*64 + ((u>>3)^(b&7))*8 + (u&7). Rows 8-15 stay zero.
  __shared__ __align__(16) unsigned short hsm[2][16][64];
  __shared__ __align__(16) unsigned short xs[T_STEPS][BPB][16];  // 64 KB
  __shared__ float red[2][4][BPB];
  unsigned short* hb = &hsm[0][0][0];
  for (int idx = tid; idx < 2*16*64; idx += 256) hb[idx] = 0;

  // ---- one-time x pre-stage: [t][b][k] f32 -> bf16, k padded to 16 ----
  for (int r = tid; r < T_STEPS*BPB; r += 256) {
    const int t = r >> 3, b = r & 7;
    const float* src = x + ((size_t)t*BATCH + b0 + b)*ISZ;
    uint32_t* dst = (uint32_t*)&xs[t][b][0];
    #pragma unroll
    for (int e2 = 0; e2 < 8; ++e2) {
      const int k0 = 2*e2, k1 = 2*e2 + 1;
      const float v0 = (k0 < ISZ) ? src[k0] : 0.f;
      const float v1 = (k1 < ISZ) ? src[k1] : 0.f;
      dst[e2] = cvt_pk_bf16(v0, v1);
    }
  }

  const int rof0 = lc*64 + ((lg     ^ (lc&7)))*8;  // A-frag units lg*8..+7
  const int rof1 = lc*64 + (((4+lg) ^ (lc&7)))*8;  // units 32+lg*8..+7
  const int wofA = bmA*64 + (((j>>3) ^ (bmA&7))*8) + (j&7);
  const int wofB = bmB*64 + (((j>>3) ^ (bmB&7))*8) + (j&7);

  // gate scales: PyTorch order i,f,g,o — sigm: -log2e, tanh: -2log2e
  const float SC[4] = {-1.44269504f, -1.44269504f, -2.88539008f, -1.44269504f};

  // ---- encoder weight fragments (prescaled, persistent in VGPRs) ----
  short8 Bh[4][2], Bx[4];
  float bias[4];
  #pragma unroll
  for (int i = 0; i < 4; ++i) {
    const int r = 64*i + j;
    const float s = SC[i];
    #pragma unroll
    for (int f = 0; f < 2; ++f) {
      S8U v;
      #pragma unroll
      for (int e2 = 0; e2 < 4; ++e2)
        v.u[e2] = cvt_pk_bf16(Whh_e[r*HID + f*32 + lg*8 + 2*e2]*s,
                              Whh_e[r*HID + f*32 + lg*8 + 2*e2 + 1]*s);
      Bh[i][f] = v.s;
    }
    S8U vx;
    #pragma unroll
    for (int e2 = 0; e2 < 4; ++e2) {
      const int k0 = lg*8 + 2*e2, k1 = k0 + 1;
      vx.u[e2] = cvt_pk_bf16(k0 < ISZ ? Wih_e[r*ISZ + k0]*s : 0.f,
                             k1 < ISZ ? Wih_e[r*ISZ + k1]*s : 0.f);
    }
    Bx[i] = vx.s;
    bias[i] = b_e[r]*s;
  }

  float cA = 0.f, cB = 0.f;
  const f32x4 vzero = {0.f, 0.f, 0.f, 0.f};
  const short8 szero = {0,0,0,0,0,0,0,0};

  lds_barrier();   // xs + h zero-init visible before prologue x read

  // prologue: accx(0) = bias + x(0)-part (h(0)=0)
  f32x4 accx[4];
  {
    short8 axf = szero;
    if (lg < 2) axf = *(const short8*)&xs[0][lc & 7][lg * 8];
    #pragma unroll
    for (int i = 0; i < 4; ++i) {
      f32x4 a = {bias[i], bias[i], bias[i], bias[i]};
      accx[i] = __builtin_amdgcn_mfma_f32_16x16x32_bf16(axf, Bx[i], a, 0, 0, 0);
    }
  }

  // ---- encoder recurrence: barrier at top, double-buffered h ----
  #pragma unroll 2
  for (int t = 0; t < T_STEPS; ++t) {
    const int s = t & 1;
    lds_barrier();                 // h(t) visible
    const unsigned short* hr = hb + s*1024;
    unsigned short*       hw = hb + (s^1)*1024;
    short8 ah0 = *(const short8*)(hr + rof0);
    short8 ah1 = *(const short8*)(hr + rof1);
    // issue next step's x read alongside the h reads (xs immutable)
    short8 axn = szero;
    if (lg < 2 && t + 1 < T_STEPS)
      axn = *(const short8*)&xs[t + 1][lc & 7][lg * 8];

    f32x4 gacc[4];
    #pragma unroll
    for (int i = 0; i < 4; ++i) {
      f32x4 a = __builtin_amdgcn_mfma_f32_16x16x32_bf16(ah0, Bh[i][0], accx[i], 0, 0, 0);
      f32x4 b = __builtin_amdgcn_mfma_f32_16x16x32_bf16(ah1, Bh[i][1], vzero,   0, 0, 0);
      gacc[i] = a + b;
    }

    // redistribute via half-wave swap: every lane gets 2 cell elements
    float gA[4], gB[4];
    #pragma unroll
    for (int i = 0; i < 4; ++i) {
      gA[i] = permswap(gacc[i][0], gacc[i][2]);
      gB[i] = permswap(gacc[i][1], gacc[i][3]);
    }
    const float iA = sigm_z(gA[0]), fA = sigm_z(gA[1]), oA = sigm_z(gA[3]);
    const float iB = sigm_z(gB[0]), fB = sigm_z(gB[1]), oB = sigm_z(gB[3]);
    const float ggA = 2.f*sigm_z(gA[2]) - 1.f;
    const float ggB = 2.f*sigm_z(gB[2]) - 1.f;
    cA = fA*cA + iA*ggA;
    cB = fB*cB + iB*ggB;
    const float thA = 2.f*sigm_z(cA * -2.88539008f) - 1.f;
    const float thB = 2.f*sigm_z(cB * -2.88539008f) - 1.f;
    const float hA = oA*thA, hB = oB*thB;

    const uint32_t pk = cvt_pk_bf16(hA, hB);
    hw[wofA] = (unsigned short)(pk & 0xffffu);
    hw[wofB] = (unsigned short)(pk >> 16);

    // ---- pre-barrier: x-MFMA for step t+1 (fills barrier-arrival skew) ----
    #pragma unroll
    for (int i = 0; i < 4; ++i) {
      f32x4 a = {bias[i], bias[i], bias[i], bias[i]};
      accx[i] = __builtin_amdgcn_mfma_f32_16x16x32_bf16(axn, Bx[i], a, 0, 0, 0);
    }
  }

  // ---- decoder weights (prescaled) ----
  #pragma unroll
  for (int i = 0; i < 4; ++i) {
    const int r = 64*i + j;
    const float s = SC[i];
    #pragma unroll
    for (int f = 0; f < 2; ++f) {
      S8U v;
      #pragma unroll
      for (int e2 = 0; e2 < 4; ++e2)
        v.u[e2] = cvt_pk_bf16(Whh_d[r*HID + f*32 + lg*8 + 2*e2]*s,
                              Whh_d[r*HID + f*32 + lg*8 + 2*e2 + 1]*s);
      Bh[i][f] = v.s;
    }
  }
  f32x4 gi[4];
  {
    float yv[4];
    #pragma unroll
    for (int r = 0; r < 4; ++r) {
      const int m = lg*4 + r;
      yv[r] = (m < BPB) ? y[b0 + m] : 0.f;
    }
    #pragma unroll
    for (int i = 0; i < 4; ++i) {
      const int r = 64*i + j;
      const float wd = Wih_d[r]*SC[i], bd = b_d[r]*SC[i];
      #pragma unroll
      for (int g = 0; g < 4; ++g) gi[i][g] = yv[g]*wd + bd;
    }
  }
  const float wfc = Wfc[j];
  const float bfv = bfc[0];

  // ---- decoder: h(T) sits in buf0 (T even); 2 barriers/step (12 steps) ----
  for (int p = 0; p < PHOR; ++p) {
    const int pb = p & 1;
    lds_barrier();               // h(p) visible
    const unsigned short* hr = hb + pb*1024;
    unsigned short*       hw = hb + (pb^1)*1024;
    short8 ah0 = *(const short8*)(hr + rof0);
    short8 ah1 = *(const short8*)(hr + rof1);
    f32x4 gacc[4];
    #pragma unroll
    for (int i = 0; i < 4; ++i) {
      f32x4 a = __builtin_amdgcn_mfma_f32_16x16x32_bf16(ah0, Bh[i][0], gi[i], 0, 0, 0);
      f32x4 b = __builtin_amdgcn_mfma_f32_16x16x32_bf16(ah1, Bh[i][1], vzero, 0, 0, 0);
      gacc[i] = a + b;
    }
    float gA[4], gB[4];
    #pragma unroll
    for (int i = 0; i < 4; ++i) {
      gA[i] = permswap(gacc[i][0], gacc[i][2]);
      gB[i] = permswap(gacc[i][1], gacc[i][3]);
    }
    const float iA = sigm_z(gA[0]), fA = sigm_z(gA[1]), oA = sigm_z(gA[3]);
    const float iB = sigm_z(gB[0]), fB = sigm_z(gB[1]), oB = sigm_z(gB[3]);
    const float ggA = 2.f*sigm_z(gA[2]) - 1.f;
    const float ggB = 2.f*sigm_z(gB[2]) - 1.f;
    cA = fA*cA + iA*ggA;
    cB = fB*cB + iB*ggB;
    const float thA = 2.f*sigm_z(cA * -2.88539008f) - 1.f;
    const float thB = 2.f*sigm_z(cB * -2.88539008f) - 1.f;
    const float hA = oA*thA, hB = oB*thB;

    const uint32_t pk = cvt_pk_bf16(hA, hB);
    hw[wofA] = (unsigned short)(pk & 0xffffu);
    hw[wofB] = (unsigned short)(pk >> 16);

    float partA = hA * wfc, partB = hB * wfc;
    #pragma unroll
    for (int m = 1; m <= 8; m <<= 1) {
      partA += __shfl_xor(partA, m, 64);
      partB += __shfl_xor(partB, m, 64);
    }
    if (lc == 0) {
      red[pb][wv][bmA] = partA;
      red[pb][wv][bmB] = partB;
    }
    lds_barrier();               // red visible
    if (tid < BPB)
      out[(size_t)p*BATCH + b0 + tid] = bfv + red[pb][0][tid] + red[pb][1][tid]
                                            + red[pb][2][tid] + red[pb][3][tid];
  }
}

extern "C" void kernel_launch(void* const* d_in, const int* in_sizes, int n_in,
                              void* d_out, int out_size, void* d_ws, size_t ws_size,
                              hipStream_t stream) {
  const float* x     = (const float*)d_in[0];
  const float* y     = (const float*)d_in[1];
  // d_in[2] = teacher_force (0 in setup; inference branch only)
  const float* Wih_e = (const float*)d_in[3];
  const float* Whh_e = (const float*)d_in[4];
  const float* b_e   = (const float*)d_in[5];
  const float* Wih_d = (const float*)d_in[6];
  const float* Whh_d = (const float*)d_in[7];
  const float* b_d   = (const float*)d_in[8];
  const float* Wfc   = (const float*)d_in[9];
  const float* bfc   = (const float*)d_in[10];
  float* out = (float*)d_out;

  lstm_fused<<<dim3(BATCH/BPB), dim3(256), 0, stream>>>(
      x, y, Wih_e, Whh_e, b_e, Wih_d, Whh_d, b_d, Wfc, bfc, out);
}